// Round 11
// baseline (892.173 us; speedup 1.0000x reference)
//
#include <hip/hip_runtime.h>
#include <hip/hip_bf16.h>

typedef _Float16 f16x8 __attribute__((ext_vector_type(8)));
typedef _Float16 f16x4 __attribute__((ext_vector_type(4)));
typedef float f32x4 __attribute__((ext_vector_type(4)));

__device__ __forceinline__ float tanh_fast(float x) {
  float e = __expf(2.0f * x);
  return 1.0f - 2.0f * __builtin_amdgcn_rcpf(e + 1.0f);
}
__device__ __forceinline__ float sigmoid_fast(float x) {
  return __builtin_amdgcn_rcpf(1.0f + __expf(-x));
}

// ---------------- K0: weight prep (unchanged) ----------------
// Fragment tiles of 512 hw. PI k-order (W2, Wq1): lane l elem j holds
// B[k = kt*32 + pi(q,j)][col = nt*16 + l15], pi(q,j) = q*4 + (j&3) + 16*(j>>2).
// Plain k-order (Wq2, W1): k = q*8 + j.
// V2p tile = kt*64 + nt; T1p tile = kt*16 + nt; T2p tile = nt*8 + kt.
__global__ __launch_bounds__(256) void prep_weights(
    const float* __restrict__ W1, const float* __restrict__ W2,
    const float* __restrict__ Wq1, const float* __restrict__ Wq2,
    _Float16* __restrict__ V1p, _Float16* __restrict__ V2p,
    _Float16* __restrict__ T1p, _Float16* __restrict__ T2p) {
  __shared__ float S[32 * 33];
  int b = blockIdx.x, t = threadIdx.x;
  if (b < 2624) {
    const float* in; _Float16* out; int N, nc0, tile, use_pi;
    if (b < 2048) {        // W2 [32][1024][32]: h, ntl, kt  (PI)
      int h = b >> 6, rem = b & 63, ntl = rem >> 5, kt = rem & 31;
      in = W2 + (size_t)h * 32768 + (size_t)kt * 32 * 32;
      N = 32; nc0 = ntl * 16;
      out = V2p; tile = kt * 64 + (h * 2 + ntl); use_pi = 1;
    } else if (b < 2560) { // Wq1 [1024][256]  (PI)
      int i = b - 2048, nt = i >> 5, kt = i & 31;
      in = Wq1 + (size_t)kt * 32 * 256; N = 256; nc0 = nt * 16;
      out = T1p; tile = kt * 16 + nt; use_pi = 1;
    } else {               // Wq2 [256][128]  (plain)
      int i = b - 2560, nt = i >> 3, kt = i & 7;
      in = Wq2 + (size_t)kt * 32 * 128; N = 128; nc0 = nt * 16;
      out = T2p; tile = nt * 8 + kt; use_pi = 0;
    }
    if (t < 128) {
      int r = t >> 2, c4 = (t & 3) * 4;
      const float4 v = *(const float4*)(in + (size_t)r * N + nc0 + c4);
      S[r * 17 + c4 + 0] = v.x; S[r * 17 + c4 + 1] = v.y;
      S[r * 17 + c4 + 2] = v.z; S[r * 17 + c4 + 3] = v.w;
    }
    __syncthreads();
    if (t < 128) {
      int w2 = t >> 6, l = t & 63, q = l >> 4, l15 = l & 15;
      f16x4 o;
#pragma unroll
      for (int jj = 0; jj < 4; ++jj) {
        int kl = use_pi ? (q * 4 + jj + w2 * 16) : (q * 8 + w2 * 4 + jj);
        o[jj] = (_Float16)S[kl * 17 + l15];
      }
      *(f16x4*)(out + (size_t)tile * 512 + l * 8 + w2 * 4) = o;
    }
  } else {                 // W1 [32][32][32]: one block per head h (plain)
    int h = b - 2624;
    const float* in = W1 + h * 1024;
    int cc = t & 31, rr8 = t >> 5;
#pragma unroll
    for (int p = 0; p < 4; ++p) {
      int r = rr8 + p * 8;
      S[cc * 33 + r] = in[r * 32 + cc];
    }
    __syncthreads();
    if (t < 128) {
      int ntl = t >> 6, l = t & 63, q = l >> 4, l15 = l & 15;
      f16x8 o;
#pragma unroll
      for (int j = 0; j < 8; ++j)
        o[j] = (_Float16)S[(ntl * 16 + l15) * 33 + q * 8 + j];
      *(f16x8*)(V1p + (size_t)(h * 2 + ntl) * 512 + l * 8) = o;
    }
  }
}

// ---------------- K12Q: fully fused ripple1+ripple2+q-network ----------------
// Block = 64 rows x 1024 cols, 512 threads = 8 waves. This round combines the
// two verified halves of the r9/r10 matched pair:
//  - register DIET (r10): produceHalf(h,buf,e) split producer (rb 8 + bs 4,
//    f16x4 stores), staggered at ktl==w (e=0) / ktl==(w+4)&7 (e=1). Removed
//    the r9 spill (WRITE 241->45 MB).
//  - xab PING-PONG (r9): A-fragments prefetched 1 ktl ahead; removing it in
//    r10 exposed ~120cyc LDS latency before each 32-MFMA cluster (555->612).
// Peak regs ~228 < 256 cap -> both fixes coexist without spill.
// Tail (verified r8-r10): acc-dump frees 128 AGPRs, then q1 GEMM / LN /
// y2 GEMM / LN / wq3 dot in-block. LDS phase-aliased 128 KB. y1h stride 268.
// launch_bounds MUST stay (512,2).
__global__ __launch_bounds__(512, 2) void k12q(
    const float* __restrict__ state, const float* __restrict__ action,
    const _Float16* __restrict__ v1p, const float* __restrict__ b1,
    const float* __restrict__ g1,
    const _Float16* __restrict__ v2p, const float* __restrict__ b2,
    const float* __restrict__ g2,
    const _Float16* __restrict__ t1p, const _Float16* __restrict__ t2p,
    const float* __restrict__ bq1, const float* __restrict__ ln1g,
    const float* __restrict__ ln1b,
    const float* __restrict__ bq2, const float* __restrict__ ln2g,
    const float* __restrict__ ln2b,
    const float* __restrict__ wq3, const float* __restrict__ bq3,
    float* __restrict__ out) {
  __shared__ __align__(16) _Float16 LB[65536];           // 128 KB, phase-aliased
  __shared__ float redA[64 * 8], redB[64 * 8];           // 4 KB
  __shared__ float meanv[64], rstdv[64];                 // 0.5 KB
  _Float16* SA  = LB;                                    // 64*40 = 2560 (K-loop)
  _Float16* XBb = LB + 2560;                             // 2 x 16384 (K-loop)
  _Float16* x2h = LB;                                    // 128 tiles x 512 (tail q1)
  _Float16* y1h = LB;                                    // 64*268 (tail y2)

  int bm = blockIdx.x;
  int t = threadIdx.x, w = t >> 6, l = t & 63, q = l >> 4, l15 = l & 15;
  int m0 = bm * 64;

  {  // stage sa tile [64][32] fp16, stride 40; 8 threads/row (4 floats each)
    int r = t >> 3, qq = t & 7;
    size_t grow = (size_t)(m0 + r);
    const float* src = (qq < 6) ? (state + grow * 24 + qq * 4)
                                : (action + grow * 8 + (qq - 6) * 4);
    float4 v = *(const float4*)src;
    f16x4 h;
    h[0] = (_Float16)v.x; h[1] = (_Float16)v.y;
    h[2] = (_Float16)v.z; h[3] = (_Float16)v.w;
    *(f16x4*)&SA[r * 40 + qq * 4] = h;
  }
  __syncthreads();

  // loop-invariant sa fragments (B operand of producer MFMAs), 64 rows
  f16x8 asa[4];
#pragma unroll
  for (int p = 0; p < 4; ++p)
    asa[p] = *(const f16x8*)&SA[(p * 16 + l15) * 40 + q * 8];

  const int nt0 = w * 8;
  const _Float16* bBase = v2p + (size_t)nt0 * 512 + (size_t)l * 8;
  f32x4 acc[4][8] = {};

  // half-head producer: e selects v1p tile 2h+e and output bytes e*8 of each
  // f16x8 slot. Two staggered calls == old produce(h,buf), at half the
  // register footprint (rb 8 + bs 4 + d 4 + o 2 transient).
  auto produceHalf = [&](int h, int buf, int e) {
    f16x8 rb = *(const f16x8*)(v1p + (size_t)(2 * h + e) * 512 + l * 8);
    float sg = sigmoid_fast(g1[h]);
    f32x4 bs = *(const f32x4*)(b1 + h * 32 + e * 16 + q * 4);
    _Float16* bw = XBb + (size_t)buf * 16384 + (size_t)((h & 7) * 4) * 512 + l * 8 + e * 4;
#pragma unroll
    for (int pp = 0; pp < 4; ++pp) {
      f32x4 d = {};
      d = __builtin_amdgcn_mfma_f32_16x16x32_f16(rb, asa[pp], d, 0, 0, 0);
      f16x4 o;
#pragma unroll
      for (int r = 0; r < 4; ++r)
        o[r] = (_Float16)(tanh_fast(d[r] + bs[r]) * sg);
      *(f16x4*)(bw + (size_t)pp * 512) = o;
    }
  };

  // prologue
  f16x8 bb0[4], bb1v[4];
#pragma unroll
  for (int n2 = 0; n2 < 4; ++n2)
    bb0[n2] = *(const f16x8*)(bBase + (size_t)n2 * 512);
#pragma unroll
  for (int n2 = 0; n2 < 4; ++n2)
    bb1v[n2] = *(const f16x8*)(bBase + (size_t)(4 + n2) * 512);
  produceHalf(w, 0, 0);
  produceHalf(w, 0, 1);
  __syncthreads();

  f16x8 xab[2][4];
#pragma unroll
  for (int p = 0; p < 4; ++p) {
    const _Float16* buf = XBb + (size_t)(p & 1) * 16384;
#pragma unroll
    for (int mi = 0; mi < 4; ++mi)
      xab[0][mi] = *(const f16x8*)(buf + (size_t)mi * 512 + l * 8);
#pragma unroll
    for (int ktl = 0; ktl < 8; ++ktl) {
      int kt = p * 8 + ktl;
      // prefetch next ktl's A-fragments (1-deep ping-pong; latency hidden
      // under this ktl's producer + 32-MFMA cluster)
      if (ktl < 7) {
#pragma unroll
        for (int mi = 0; mi < 4; ++mi)
          xab[(ktl + 1) & 1][mi] =
              *(const f16x8*)(buf + (size_t)((ktl + 1) * 4 + mi) * 512 + l * 8);
      }
      // staggered half-head producers (next phase's buffer)
      if (ktl == w && p < 3) produceHalf((p + 1) * 8 + w, (p & 1) ^ 1, 0);
      if (ktl == ((w + 4) & 7) && p < 3) produceHalf((p + 1) * 8 + w, (p & 1) ^ 1, 1);
      __builtin_amdgcn_s_setprio(1);
#pragma unroll
      for (int mi = 0; mi < 4; ++mi)
#pragma unroll
        for (int n2 = 0; n2 < 4; ++n2)
          acc[mi][n2] = __builtin_amdgcn_mfma_f32_16x16x32_f16(
              bb0[n2], xab[ktl & 1][mi], acc[mi][n2], 0, 0, 0);
      if (kt < 31) {
#pragma unroll
        for (int n2 = 0; n2 < 4; ++n2)
          bb0[n2] = *(const f16x8*)(bBase + (size_t)((kt + 1) * 64 + n2) * 512);
      }
#pragma unroll
      for (int mi = 0; mi < 4; ++mi)
#pragma unroll
        for (int n2 = 0; n2 < 4; ++n2)
          acc[mi][4 + n2] = __builtin_amdgcn_mfma_f32_16x16x32_f16(
              bb1v[n2], xab[ktl & 1][mi], acc[mi][4 + n2], 0, 0, 0);
      if (kt < 31) {
#pragma unroll
        for (int n2 = 0; n2 < 4; ++n2)
          bb1v[n2] = *(const f16x8*)(bBase + (size_t)((kt + 1) * 64 + 4 + n2) * 512);
      }
      __builtin_amdgcn_s_setprio(0);
    }
    if (p < 3) __syncthreads();
  }

  // ---------------- fused q-network tail ----------------
  __syncthreads();  // all XB reads done before aliasing LB as x2h

  // dump ALL acc tiles: wave w owns kc2 = w*4..w*4+3 -> x2h tile kc2*4+mi.
  // After this, acc is dead (frees 128 AGPRs for the tail).
#pragma unroll
  for (int mi = 0; mi < 4; ++mi)
#pragma unroll
    for (int p2 = 0; p2 < 4; ++p2) {
      int kc2 = w * 4 + p2;   // == nt0>>1 + p2
      float sg2 = sigmoid_fast(g2[kc2]);
      f32x4 c0 = *(const f32x4*)(b2 + kc2 * 32 + q * 4);
      f32x4 c1 = *(const f32x4*)(b2 + kc2 * 32 + 16 + q * 4);
      f16x8 o;
#pragma unroll
      for (int r = 0; r < 4; ++r) {
        o[r]     = (_Float16)(tanh_fast(acc[mi][2 * p2][r] + c0[r]) * sg2);
        o[4 + r] = (_Float16)(tanh_fast(acc[mi][2 * p2 + 1][r] + c1[r]) * sg2);
      }
      *(f16x8*)(x2h + (size_t)(kc2 * 4 + mi) * 512 + l * 8) = o;
    }
  __syncthreads();

  // q1 GEMM: kt 0..31, 1-deep prefetch of A (LDS) and B (L2) frags
  f32x4 acc2[4][2] = {};
  {
    f16x8 aC[4], aN[4], bf0C, bf1C, bf0N, bf1N;
#pragma unroll
    for (int mi = 0; mi < 4; ++mi)
      aC[mi] = *(const f16x8*)(x2h + (size_t)mi * 512 + l * 8);
    bf0C = *(const f16x8*)(t1p + (size_t)(w * 2) * 512 + l * 8);
    bf1C = *(const f16x8*)(t1p + (size_t)(w * 2 + 1) * 512 + l * 8);
#pragma unroll
    for (int kt = 0; kt < 32; ++kt) {
      if (kt < 31) {
#pragma unroll
        for (int mi = 0; mi < 4; ++mi)
          aN[mi] = *(const f16x8*)(x2h + (size_t)((kt + 1) * 4 + mi) * 512 + l * 8);
        bf0N = *(const f16x8*)(t1p + (size_t)((kt + 1) * 16 + w * 2) * 512 + l * 8);
        bf1N = *(const f16x8*)(t1p + (size_t)((kt + 1) * 16 + w * 2 + 1) * 512 + l * 8);
      }
#pragma unroll
      for (int mi = 0; mi < 4; ++mi) {
        acc2[mi][0] = __builtin_amdgcn_mfma_f32_16x16x32_f16(aC[mi], bf0C, acc2[mi][0], 0, 0, 0);
        acc2[mi][1] = __builtin_amdgcn_mfma_f32_16x16x32_f16(aC[mi], bf1C, acc2[mi][1], 0, 0, 0);
      }
#pragma unroll
      for (int mi = 0; mi < 4; ++mi) aC[mi] = aN[mi];
      bf0C = bf0N; bf1C = bf1N;
    }
  }

  // bias + LN over 256 cols
#pragma unroll
  for (int ni = 0; ni < 2; ++ni) {
    int col = w * 32 + ni * 16 + l15;
    float b = bq1[col];
#pragma unroll
    for (int mi = 0; mi < 4; ++mi)
#pragma unroll
      for (int r = 0; r < 4; ++r) acc2[mi][ni][r] += b;
  }
#pragma unroll
  for (int mi = 0; mi < 4; ++mi)
#pragma unroll
    for (int r = 0; r < 4; ++r) {
      int row = mi * 16 + q * 4 + r;
      float s = 0.f, sq = 0.f;
#pragma unroll
      for (int ni = 0; ni < 2; ++ni) { float v = acc2[mi][ni][r]; s += v; sq += v * v; }
#pragma unroll
      for (int off = 1; off < 16; off <<= 1) { s += __shfl_xor(s, off); sq += __shfl_xor(sq, off); }
      if (l15 == 0) { redA[row * 8 + w] = s; redB[row * 8 + w] = sq; }
    }
  __syncthreads();  // also: all x2h reads complete past this point
  if (t < 64) {
    float s = 0.f, sq = 0.f;
#pragma unroll
    for (int i = 0; i < 8; ++i) { s += redA[t * 8 + i]; sq += redB[t * 8 + i]; }
    float mean = s * (1.0f / 256.0f);
    float var = sq * (1.0f / 256.0f) - mean * mean;
    meanv[t] = mean; rstdv[t] = rsqrtf(var + 1e-5f);
  }
  __syncthreads();
#pragma unroll
  for (int mi = 0; mi < 4; ++mi)
#pragma unroll
    for (int ni = 0; ni < 2; ++ni)
#pragma unroll
      for (int r = 0; r < 4; ++r) {
        int row = mi * 16 + q * 4 + r;
        int col = w * 32 + ni * 16 + l15;
        float y = (acc2[mi][ni][r] - meanv[row]) * rstdv[row] * ln1g[col] + ln1b[col];
        y = fmaxf(y, 0.f);
        y1h[row * 268 + col] = (_Float16)y;   // y1h aliases LB (x2h dead)
      }
  __syncthreads();

  // y2 GEMM: wave w owns cols w*16..w*16+15 (T2p tile nt=w, plain k-order)
  f32x4 a3[4] = {};
  for (int kt = 0; kt < 8; ++kt) {
    f16x8 af[4];
#pragma unroll
    for (int mi = 0; mi < 4; ++mi)
      af[mi] = *(const f16x8*)&y1h[(mi * 16 + l15) * 268 + kt * 32 + q * 8];
    f16x8 bf = *(const f16x8*)(t2p + (size_t)(w * 8 + kt) * 512 + l * 8);
#pragma unroll
    for (int mi = 0; mi < 4; ++mi)
      a3[mi] = __builtin_amdgcn_mfma_f32_16x16x32_f16(af[mi], bf, a3[mi], 0, 0, 0);
  }
  {
    int col = w * 16 + l15;
    float b = bq2[col];
#pragma unroll
    for (int mi = 0; mi < 4; ++mi)
#pragma unroll
      for (int r = 0; r < 4; ++r) a3[mi][r] += b;
  }
  __syncthreads();  // y1h reads done; redA/redB reuse safe
#pragma unroll
  for (int mi = 0; mi < 4; ++mi)
#pragma unroll
    for (int r = 0; r < 4; ++r) {
      int row = mi * 16 + q * 4 + r;
      float s = a3[mi][r], sq = s * s;
#pragma unroll
      for (int off = 1; off < 16; off <<= 1) { s += __shfl_xor(s, off); sq += __shfl_xor(sq, off); }
      if (l15 == 0) { redA[row * 8 + w] = s; redB[row * 8 + w] = sq; }
    }
  __syncthreads();
  if (t < 64) {
    float s = 0.f, sq = 0.f;
#pragma unroll
    for (int i = 0; i < 8; ++i) { s += redA[t * 8 + i]; sq += redB[t * 8 + i]; }
    float mean = s * (1.0f / 128.0f);
    float var = sq * (1.0f / 128.0f) - mean * mean;
    meanv[t] = mean; rstdv[t] = rsqrtf(var + 1e-5f);
  }
  __syncthreads();
#pragma unroll
  for (int mi = 0; mi < 4; ++mi)
#pragma unroll
    for (int r = 0; r < 4; ++r) {
      int row = mi * 16 + q * 4 + r;
      int col = w * 16 + l15;
      float y = (a3[mi][r] - meanv[row]) * rstdv[row] * ln2g[col] + ln2b[col];
      y = fmaxf(y, 0.f);
      float pr = y * wq3[col];
#pragma unroll
      for (int off = 1; off < 16; off <<= 1) pr += __shfl_xor(pr, off);
      if (l15 == 0) redA[row * 8 + w] = pr;
    }
  __syncthreads();
  if (t < 64) {
    float s = 0.f;
#pragma unroll
    for (int i = 0; i < 8; ++i) s += redA[t * 8 + i];
    out[m0 + t] = s + bq3[0];
  }
}

// ---------------- launcher ----------------
extern "C" void kernel_launch(void* const* d_in, const int* in_sizes, int n_in,
                              void* d_out, int out_size, void* d_ws, size_t ws_size,
                              hipStream_t stream) {
  const float* state  = (const float*)d_in[0];
  const float* action = (const float*)d_in[1];
  const float* W1  = (const float*)d_in[2];
  const float* b1  = (const float*)d_in[3];
  const float* g1  = (const float*)d_in[4];
  const float* W2  = (const float*)d_in[5];
  const float* b2  = (const float*)d_in[6];
  const float* g2  = (const float*)d_in[7];
  const float* Wq1 = (const float*)d_in[8];
  const float* bq1 = (const float*)d_in[9];
  const float* ln1g = (const float*)d_in[10];
  const float* ln1b = (const float*)d_in[11];
  const float* Wq2 = (const float*)d_in[12];
  const float* bq2 = (const float*)d_in[13];
  const float* ln2g = (const float*)d_in[14];
  const float* ln2b = (const float*)d_in[15];
  const float* Wq3 = (const float*)d_in[16];
  const float* bq3 = (const float*)d_in[17];
  int B = in_sizes[0] / 24;

  char* ws = (char*)d_ws;
  _Float16* V1p = (_Float16*)(ws);
  _Float16* V2p = (_Float16*)(ws + 65536);
  _Float16* T1p = (_Float16*)(ws + 65536 + 2097152);
  _Float16* T2p = (_Float16*)(ws + 65536 + 2097152 + 524288);

  prep_weights<<<2656, 256, 0, stream>>>(W1, W2, Wq1, Wq2, V1p, V2p, T1p, T2p);

  int nb = B / 64;
  k12q<<<dim3(nb), 512, 0, stream>>>(state, action, V1p, b1, g1,
                                     V2p, b2, g2, T1p, T2p,
                                     bq1, ln1g, ln1b, bq2, ln2g, ln2b,
                                     Wq3, bq3, (float*)d_out);
}

// Round 12
// 615.929 us; speedup vs baseline: 1.4485x; 1.4485x over previous
//
#include <hip/hip_runtime.h>
#include <hip/hip_bf16.h>

typedef _Float16 f16x8 __attribute__((ext_vector_type(8)));
typedef _Float16 f16x4 __attribute__((ext_vector_type(4)));
typedef float f32x4 __attribute__((ext_vector_type(4)));

__device__ __forceinline__ float tanh_fast(float x) {
  float e = __expf(2.0f * x);
  return 1.0f - 2.0f * __builtin_amdgcn_rcpf(e + 1.0f);
}
__device__ __forceinline__ float sigmoid_fast(float x) {
  return __builtin_amdgcn_rcpf(1.0f + __expf(-x));
}

// ---------------- K0: weight prep (unchanged) ----------------
// Fragment tiles of 512 hw. PI k-order (W2, Wq1): lane l elem j holds
// B[k = kt*32 + pi(q,j)][col = nt*16 + l15], pi(q,j) = q*4 + (j&3) + 16*(j>>2).
// Plain k-order (Wq2, W1): k = q*8 + j.
// V2p tile = kt*64 + nt; T1p tile = kt*16 + nt; T2p tile = nt*8 + kt.
__global__ __launch_bounds__(256) void prep_weights(
    const float* __restrict__ W1, const float* __restrict__ W2,
    const float* __restrict__ Wq1, const float* __restrict__ Wq2,
    _Float16* __restrict__ V1p, _Float16* __restrict__ V2p,
    _Float16* __restrict__ T1p, _Float16* __restrict__ T2p) {
  __shared__ float S[32 * 33];
  int b = blockIdx.x, t = threadIdx.x;
  if (b < 2624) {
    const float* in; _Float16* out; int N, nc0, tile, use_pi;
    if (b < 2048) {        // W2 [32][1024][32]: h, ntl, kt  (PI)
      int h = b >> 6, rem = b & 63, ntl = rem >> 5, kt = rem & 31;
      in = W2 + (size_t)h * 32768 + (size_t)kt * 32 * 32;
      N = 32; nc0 = ntl * 16;
      out = V2p; tile = kt * 64 + (h * 2 + ntl); use_pi = 1;
    } else if (b < 2560) { // Wq1 [1024][256]  (PI)
      int i = b - 2048, nt = i >> 5, kt = i & 31;
      in = Wq1 + (size_t)kt * 32 * 256; N = 256; nc0 = nt * 16;
      out = T1p; tile = kt * 16 + nt; use_pi = 1;
    } else {               // Wq2 [256][128]  (plain)
      int i = b - 2560, nt = i >> 3, kt = i & 7;
      in = Wq2 + (size_t)kt * 32 * 128; N = 128; nc0 = nt * 16;
      out = T2p; tile = nt * 8 + kt; use_pi = 0;
    }
    if (t < 128) {
      int r = t >> 2, c4 = (t & 3) * 4;
      const float4 v = *(const float4*)(in + (size_t)r * N + nc0 + c4);
      S[r * 17 + c4 + 0] = v.x; S[r * 17 + c4 + 1] = v.y;
      S[r * 17 + c4 + 2] = v.z; S[r * 17 + c4 + 3] = v.w;
    }
    __syncthreads();
    if (t < 128) {
      int w2 = t >> 6, l = t & 63, q = l >> 4, l15 = l & 15;
      f16x4 o;
#pragma unroll
      for (int jj = 0; jj < 4; ++jj) {
        int kl = use_pi ? (q * 4 + jj + w2 * 16) : (q * 8 + w2 * 4 + jj);
        o[jj] = (_Float16)S[kl * 17 + l15];
      }
      *(f16x4*)(out + (size_t)tile * 512 + l * 8 + w2 * 4) = o;
    }
  } else {                 // W1 [32][32][32]: one block per head h (plain)
    int h = b - 2624;
    const float* in = W1 + h * 1024;
    int cc = t & 31, rr8 = t >> 5;
#pragma unroll
    for (int p = 0; p < 4; ++p) {
      int r = rr8 + p * 8;
      S[cc * 33 + r] = in[r * 32 + cc];
    }
    __syncthreads();
    if (t < 128) {
      int ntl = t >> 6, l = t & 63, q = l >> 4, l15 = l & 15;
      f16x8 o;
#pragma unroll
      for (int j = 0; j < 8; ++j)
        o[j] = (_Float16)S[(ntl * 16 + l15) * 33 + q * 8 + j];
      *(f16x8*)(V1p + (size_t)(h * 2 + ntl) * 512 + l * 8) = o;
    }
  }
}

// ---------------- K12: fused ripple1+ripple2, 64x1024 blocks (r4 verified) --
// Block = 64 rows x FULL 1024 cols, 512 threads = 8 waves; wave = 64 rows x
// 128 cols (nt0 = w*8), acc[4][8]. Ripple1 redundancy = 1x: block produces
// its own x1 tile once into a 2x64KB LDS dbuf (16 k-tiles per buffer) and
// consumes all 32 k-tiles. 3 barriers/block; ph1 production (heads 16..31)
// interleaved into ph0 consumption at ktl==6/10, writing buf1 while buf0 is
// read. A-fragments ping-pong in registers (xab[2][4], full unroll). LDS
// 136 KB -> 1 block/CU, 2 waves/SIMD (acc[4][8]=128 AGPR + 128 VGPR is the
// hard register cap — launch_bounds MUST stay (512,2); (512,4) forces
// VGPR=64 and catastrophic spill, r5). Measured 90.4 µs/slice (r4).
__global__ __launch_bounds__(512, 2) void k12_fused(
    const float* __restrict__ state, const float* __restrict__ action,
    const _Float16* __restrict__ v1p, const float* __restrict__ b1,
    const float* __restrict__ g1,
    const _Float16* __restrict__ v2p, const float* __restrict__ b2,
    const float* __restrict__ g2,
    _Float16* __restrict__ x2p, int gro, int NRT) {
  __shared__ __align__(16) _Float16 SA[64 * 40];          // 5 KB
  __shared__ __align__(16) _Float16 XB[2][16 * 4 * 512];  // 2 x 64 KB
  int bm = blockIdx.x;
  int t = threadIdx.x, w = t >> 6, l = t & 63, q = l >> 4, l15 = l & 15;
  int m0 = bm * 64;

  {  // stage sa tile [64][32] fp16, stride 40; 8 threads/row (4 floats each)
    int r = t >> 3, qq = t & 7;
    size_t grow = (size_t)(gro + m0 + r);
    const float* src = (qq < 6) ? (state + grow * 24 + qq * 4)
                                : (action + grow * 8 + (qq - 6) * 4);
    float4 v = *(const float4*)src;
    f16x4 h;
    h[0] = (_Float16)v.x; h[1] = (_Float16)v.y;
    h[2] = (_Float16)v.z; h[3] = (_Float16)v.w;
    *(f16x4*)&SA[r * 40 + qq * 4] = h;
  }
  __syncthreads();

  // loop-invariant sa fragments (B operand of producer MFMAs), 64 rows
  f16x8 asa[4];
#pragma unroll
  for (int p = 0; p < 4; ++p)
    asa[p] = *(const f16x8*)&SA[(p * 16 + l15) * 40 + q * 8];

  const int nt0 = w * 8;
  const _Float16* bBase = v2p + (size_t)nt0 * 512 + (size_t)l * 8;
  f32x4 acc[4][8] = {};

  // produce head h (x1 cols h*32..h*32+31) for the block's 64 rows into
  // XB[buf] tiles (h&15)*4 + p. Content layout identical to verified kernel.
  auto produce = [&](int h, int buf) {
    f16x8 rb0 = *(const f16x8*)(v1p + (size_t)(2 * h) * 512 + l * 8);
    f16x8 rb1 = *(const f16x8*)(v1p + (size_t)(2 * h + 1) * 512 + l * 8);
    float sg = sigmoid_fast(g1[h]);
    f32x4 bs0 = *(const f32x4*)(b1 + h * 32 + q * 4);
    f32x4 bs1 = *(const f32x4*)(b1 + h * 32 + 16 + q * 4);
    _Float16* bw = &XB[buf][(size_t)((h & 15) * 4) * 512 + l * 8];
#pragma unroll
    for (int p = 0; p < 4; ++p) {
      f32x4 d0 = {}, d1 = {};
      d0 = __builtin_amdgcn_mfma_f32_16x16x32_f16(rb0, asa[p], d0, 0, 0, 0);
      d1 = __builtin_amdgcn_mfma_f32_16x16x32_f16(rb1, asa[p], d1, 0, 0, 0);
      f16x8 o;
#pragma unroll
      for (int r = 0; r < 4; ++r) {
        o[r]     = (_Float16)(tanh_fast(d0[r] + bs0[r]) * sg);
        o[4 + r] = (_Float16)(tanh_fast(d1[r] + bs1[r]) * sg);
      }
      *(f16x8*)(bw + (size_t)p * 512) = o;
    }
  };

  // prologue: B stream kt=0 (latency hidden under produce) + produce ph0
  f16x8 bb0[4], bb1v[4];
#pragma unroll
  for (int n2 = 0; n2 < 4; ++n2)
    bb0[n2] = *(const f16x8*)(bBase + (size_t)n2 * 512);
#pragma unroll
  for (int n2 = 0; n2 < 4; ++n2)
    bb1v[n2] = *(const f16x8*)(bBase + (size_t)(4 + n2) * 512);
  produce(w * 2, 0);
  produce(w * 2 + 1, 0);
  __syncthreads();

  f16x8 xab[2][4];
#pragma unroll
  for (int mi = 0; mi < 4; ++mi)
    xab[0][mi] = *(const f16x8*)&XB[0][(size_t)mi * 512 + l * 8];

  // phase 0: kt 0..15 from XB[0]; interleave production of heads 16..31
#pragma unroll
  for (int ktl = 0; ktl < 16; ++ktl) {
    int kt = ktl;
    if (ktl == 6)  produce(16 + w * 2, 1);
    if (ktl == 10) produce(16 + w * 2 + 1, 1);
    if (ktl < 15) {
#pragma unroll
      for (int mi = 0; mi < 4; ++mi)
        xab[(ktl + 1) & 1][mi] =
            *(const f16x8*)&XB[0][(size_t)((ktl + 1) * 4 + mi) * 512 + l * 8];
    }
    // half 0 (ni 0..3)
#pragma unroll
    for (int mi = 0; mi < 4; ++mi)
#pragma unroll
      for (int n2 = 0; n2 < 4; ++n2)
        acc[mi][n2] = __builtin_amdgcn_mfma_f32_16x16x32_f16(
            bb0[n2], xab[ktl & 1][mi], acc[mi][n2], 0, 0, 0);
#pragma unroll
    for (int n2 = 0; n2 < 4; ++n2)
      bb0[n2] = *(const f16x8*)(bBase + (size_t)((kt + 1) * 64 + n2) * 512);
    // half 1 (ni 4..7)
#pragma unroll
    for (int mi = 0; mi < 4; ++mi)
#pragma unroll
      for (int n2 = 0; n2 < 4; ++n2)
        acc[mi][4 + n2] = __builtin_amdgcn_mfma_f32_16x16x32_f16(
            bb1v[n2], xab[ktl & 1][mi], acc[mi][4 + n2], 0, 0, 0);
#pragma unroll
    for (int n2 = 0; n2 < 4; ++n2)
      bb1v[n2] = *(const f16x8*)(bBase + (size_t)((kt + 1) * 64 + 4 + n2) * 512);
  }
  __syncthreads();

#pragma unroll
  for (int mi = 0; mi < 4; ++mi)
    xab[0][mi] = *(const f16x8*)&XB[1][(size_t)mi * 512 + l * 8];

  // phase 1: kt 16..31 from XB[1]
#pragma unroll
  for (int ktl = 0; ktl < 16; ++ktl) {
    int kt = 16 + ktl;
    if (ktl < 15) {
#pragma unroll
      for (int mi = 0; mi < 4; ++mi)
        xab[(ktl + 1) & 1][mi] =
            *(const f16x8*)&XB[1][(size_t)((ktl + 1) * 4 + mi) * 512 + l * 8];
    }
    // half 0 (ni 0..3)
#pragma unroll
    for (int mi = 0; mi < 4; ++mi)
#pragma unroll
      for (int n2 = 0; n2 < 4; ++n2)
        acc[mi][n2] = __builtin_amdgcn_mfma_f32_16x16x32_f16(
            bb0[n2], xab[ktl & 1][mi], acc[mi][n2], 0, 0, 0);
    if (kt < 31) {
#pragma unroll
      for (int n2 = 0; n2 < 4; ++n2)
        bb0[n2] = *(const f16x8*)(bBase + (size_t)((kt + 1) * 64 + n2) * 512);
    }
    // half 1 (ni 4..7)
#pragma unroll
    for (int mi = 0; mi < 4; ++mi)
#pragma unroll
      for (int n2 = 0; n2 < 4; ++n2)
        acc[mi][4 + n2] = __builtin_amdgcn_mfma_f32_16x16x32_f16(
            bb1v[n2], xab[ktl & 1][mi], acc[mi][4 + n2], 0, 0, 0);
    if (kt < 31) {
#pragma unroll
      for (int n2 = 0; n2 < 4; ++n2)
        bb1v[n2] = *(const f16x8*)(bBase + (size_t)((kt + 1) * 64 + 4 + n2) * 512);
    }
  }

  // epilogue: tanh+gate in registers -> direct fragment-major x2p stores
#pragma unroll
  for (int mi = 0; mi < 4; ++mi) {
    int rt = bm * 4 + mi;
#pragma unroll
    for (int p2 = 0; p2 < 4; ++p2) {
      int kc2 = (nt0 >> 1) + p2;
      float sg2 = sigmoid_fast(g2[kc2]);
      f32x4 c0 = *(const f32x4*)(b2 + kc2 * 32 + q * 4);
      f32x4 c1 = *(const f32x4*)(b2 + kc2 * 32 + 16 + q * 4);
      f16x8 o;
#pragma unroll
      for (int r = 0; r < 4; ++r) {
        o[r]     = (_Float16)(tanh_fast(acc[mi][2 * p2][r] + c0[r]) * sg2);
        o[4 + r] = (_Float16)(tanh_fast(acc[mi][2 * p2 + 1][r] + c1[r]) * sg2);
      }
      *(f16x8*)(x2p + ((size_t)kc2 * NRT + rt) * 512 + l * 8) = o;
    }
  }
}

// ---------------- K3: q-network head, 64-row blocks ----------------
// Body = the k12q tail (verified passing r8-r11), with the q1 A-operand read
// from gmem x2p tiles (kt*NRT + rt0+mi) instead of LDS. 64-row blocks double
// the grid (512 vs 256) -> 2 blocks/CU, 4 waves/SIMD (old 128-row k3 was
// grid=256 = 1 block/CU, 2 waves/SIMD, latency-bound). Wave w owns q1 cols
// w*32..w*32+31 (T1p tiles kt*16 + w*2{,+1}) and y2 col-tile nt=w. Peak regs
// ~130 < 170 cap at launch_bounds(512,3) -> no spill. LDS ~39 KB.
__global__ __launch_bounds__(512, 3) void k3_head64(
    const _Float16* __restrict__ x2p, const _Float16* __restrict__ t1p,
    const _Float16* __restrict__ t2p,
    const float* __restrict__ bq1, const float* __restrict__ ln1g,
    const float* __restrict__ ln1b,
    const float* __restrict__ bq2, const float* __restrict__ ln2g,
    const float* __restrict__ ln2b,
    const float* __restrict__ wq3, const float* __restrict__ bq3,
    float* __restrict__ out, int NRT) {
  __shared__ __align__(16) _Float16 y1h[64 * 268];       // 33.5 KB
  __shared__ float redA[64 * 8], redB[64 * 8];           // 4 KB
  __shared__ float meanv[64], rstdv[64];                 // 0.5 KB
  int bm = blockIdx.x;
  int t = threadIdx.x, w = t >> 6, l = t & 63, q = l >> 4, l15 = l & 15;
  int rt0 = bm * 4;

  // q1 GEMM: kt 0..31, A from gmem x2p (tile kt*NRT + rt0+mi), B from t1p
  // (tile kt*16 + w*2+ni); 1-deep prefetch on both.
  f32x4 acc2[4][2] = {};
  {
    const _Float16* aBase = x2p + (size_t)rt0 * 512 + (size_t)l * 8;
    const size_t aK = (size_t)NRT * 512;
    f16x8 aC[4], aN[4], bf0C, bf1C, bf0N, bf1N;
#pragma unroll
    for (int mi = 0; mi < 4; ++mi)
      aC[mi] = *(const f16x8*)(aBase + (size_t)mi * 512);
    bf0C = *(const f16x8*)(t1p + (size_t)(w * 2) * 512 + l * 8);
    bf1C = *(const f16x8*)(t1p + (size_t)(w * 2 + 1) * 512 + l * 8);
#pragma unroll
    for (int kt = 0; kt < 32; ++kt) {
      if (kt < 31) {
#pragma unroll
        for (int mi = 0; mi < 4; ++mi)
          aN[mi] = *(const f16x8*)(aBase + (size_t)(kt + 1) * aK + (size_t)mi * 512);
        bf0N = *(const f16x8*)(t1p + (size_t)((kt + 1) * 16 + w * 2) * 512 + l * 8);
        bf1N = *(const f16x8*)(t1p + (size_t)((kt + 1) * 16 + w * 2 + 1) * 512 + l * 8);
      }
#pragma unroll
      for (int mi = 0; mi < 4; ++mi) {
        acc2[mi][0] = __builtin_amdgcn_mfma_f32_16x16x32_f16(aC[mi], bf0C, acc2[mi][0], 0, 0, 0);
        acc2[mi][1] = __builtin_amdgcn_mfma_f32_16x16x32_f16(aC[mi], bf1C, acc2[mi][1], 0, 0, 0);
      }
#pragma unroll
      for (int mi = 0; mi < 4; ++mi) aC[mi] = aN[mi];
      bf0C = bf0N; bf1C = bf1N;
    }
  }

  // bias + LN over 256 cols
#pragma unroll
  for (int ni = 0; ni < 2; ++ni) {
    int col = w * 32 + ni * 16 + l15;
    float b = bq1[col];
#pragma unroll
    for (int mi = 0; mi < 4; ++mi)
#pragma unroll
      for (int r = 0; r < 4; ++r) acc2[mi][ni][r] += b;
  }
#pragma unroll
  for (int mi = 0; mi < 4; ++mi)
#pragma unroll
    for (int r = 0; r < 4; ++r) {
      int row = mi * 16 + q * 4 + r;
      float s = 0.f, sq = 0.f;
#pragma unroll
      for (int ni = 0; ni < 2; ++ni) { float v = acc2[mi][ni][r]; s += v; sq += v * v; }
#pragma unroll
      for (int off = 1; off < 16; off <<= 1) { s += __shfl_xor(s, off); sq += __shfl_xor(sq, off); }
      if (l15 == 0) { redA[row * 8 + w] = s; redB[row * 8 + w] = sq; }
    }
  __syncthreads();
  if (t < 64) {
    float s = 0.f, sq = 0.f;
#pragma unroll
    for (int i = 0; i < 8; ++i) { s += redA[t * 8 + i]; sq += redB[t * 8 + i]; }
    float mean = s * (1.0f / 256.0f);
    float var = sq * (1.0f / 256.0f) - mean * mean;
    meanv[t] = mean; rstdv[t] = rsqrtf(var + 1e-5f);
  }
  __syncthreads();
#pragma unroll
  for (int mi = 0; mi < 4; ++mi)
#pragma unroll
    for (int ni = 0; ni < 2; ++ni)
#pragma unroll
      for (int r = 0; r < 4; ++r) {
        int row = mi * 16 + q * 4 + r;
        int col = w * 32 + ni * 16 + l15;
        float y = (acc2[mi][ni][r] - meanv[row]) * rstdv[row] * ln1g[col] + ln1b[col];
        y = fmaxf(y, 0.f);
        y1h[row * 268 + col] = (_Float16)y;
      }
  __syncthreads();

  // y2 GEMM: wave w owns cols w*16..w*16+15 (T2p tile nt=w, plain k-order)
  f32x4 a3[4] = {};
  for (int kt = 0; kt < 8; ++kt) {
    f16x8 af[4];
#pragma unroll
    for (int mi = 0; mi < 4; ++mi)
      af[mi] = *(const f16x8*)&y1h[(mi * 16 + l15) * 268 + kt * 32 + q * 8];
    f16x8 bf = *(const f16x8*)(t2p + (size_t)(w * 8 + kt) * 512 + l * 8);
#pragma unroll
    for (int mi = 0; mi < 4; ++mi)
      a3[mi] = __builtin_amdgcn_mfma_f32_16x16x32_f16(af[mi], bf, a3[mi], 0, 0, 0);
  }
  {
    int col = w * 16 + l15;
    float b = bq2[col];
#pragma unroll
    for (int mi = 0; mi < 4; ++mi)
#pragma unroll
      for (int r = 0; r < 4; ++r) a3[mi][r] += b;
  }
  __syncthreads();  // y1h reads done; redA/redB reuse safe
#pragma unroll
  for (int mi = 0; mi < 4; ++mi)
#pragma unroll
    for (int r = 0; r < 4; ++r) {
      int row = mi * 16 + q * 4 + r;
      float s = a3[mi][r], sq = s * s;
#pragma unroll
      for (int off = 1; off < 16; off <<= 1) { s += __shfl_xor(s, off); sq += __shfl_xor(sq, off); }
      if (l15 == 0) { redA[row * 8 + w] = s; redB[row * 8 + w] = sq; }
    }
  __syncthreads();
  if (t < 64) {
    float s = 0.f, sq = 0.f;
#pragma unroll
    for (int i = 0; i < 8; ++i) { s += redA[t * 8 + i]; sq += redB[t * 8 + i]; }
    float mean = s * (1.0f / 128.0f);
    float var = sq * (1.0f / 128.0f) - mean * mean;
    meanv[t] = mean; rstdv[t] = rsqrtf(var + 1e-5f);
  }
  __syncthreads();
#pragma unroll
  for (int mi = 0; mi < 4; ++mi)
#pragma unroll
    for (int r = 0; r < 4; ++r) {
      int row = mi * 16 + q * 4 + r;
      int col = w * 16 + l15;
      float y = (a3[mi][r] - meanv[row]) * rstdv[row] * ln2g[col] + ln2b[col];
      y = fmaxf(y, 0.f);
      float pr = y * wq3[col];
#pragma unroll
      for (int off = 1; off < 16; off <<= 1) pr += __shfl_xor(pr, off);
      if (l15 == 0) redA[row * 8 + w] = pr;
    }
  __syncthreads();
  if (t < 64) {
    float s = 0.f;
#pragma unroll
    for (int i = 0; i < 8; ++i) s += redA[t * 8 + i];
    out[bm * 64 + t] = s + bq3[0];
  }
}

// ---------------- launcher ----------------
extern "C" void kernel_launch(void* const* d_in, const int* in_sizes, int n_in,
                              void* d_out, int out_size, void* d_ws, size_t ws_size,
                              hipStream_t stream) {
  const float* state  = (const float*)d_in[0];
  const float* action = (const float*)d_in[1];
  const float* W1  = (const float*)d_in[2];
  const float* b1  = (const float*)d_in[3];
  const float* g1  = (const float*)d_in[4];
  const float* W2  = (const float*)d_in[5];
  const float* b2  = (const float*)d_in[6];
  const float* g2  = (const float*)d_in[7];
  const float* Wq1 = (const float*)d_in[8];
  const float* bq1 = (const float*)d_in[9];
  const float* ln1g = (const float*)d_in[10];
  const float* ln1b = (const float*)d_in[11];
  const float* Wq2 = (const float*)d_in[12];
  const float* bq2 = (const float*)d_in[13];
  const float* ln2g = (const float*)d_in[14];
  const float* ln2b = (const float*)d_in[15];
  const float* Wq3 = (const float*)d_in[16];
  const float* bq3 = (const float*)d_in[17];
  int B = in_sizes[0] / 24;

  char* ws = (char*)d_ws;
  _Float16* V1p = (_Float16*)(ws);
  _Float16* V2p = (_Float16*)(ws + 65536);
  _Float16* T1p = (_Float16*)(ws + 65536 + 2097152);
  _Float16* T2p = (_Float16*)(ws + 65536 + 2097152 + 524288);
  size_t woff = (65536 + 2097152 + 524288 + 65536 + 4095) & ~(size_t)4095;

  size_t avail = ws_size > woff ? ws_size - woff : 0;
  long rows = (long)(avail / 2048);     // x2 fp16 1024-wide
  if (rows > 32768) rows = 32768;
  rows &= ~127L;
  if (rows < 128) rows = 128;
  int S = (int)rows;
  _Float16* x2 = (_Float16*)(ws + woff);
  int NRT = S / 16;

  prep_weights<<<2656, 256, 0, stream>>>(W1, W2, Wq1, Wq2, V1p, V2p, T1p, T2p);

  for (int r0 = 0; r0 < B; r0 += S) {
    int Sc = S < (B - r0) ? S : (B - r0);
    k12_fused<<<dim3(Sc / 64), 512, 0, stream>>>(state, action, V1p, b1, g1,
                                                 V2p, b2, g2, x2, r0, NRT);
    k3_head64<<<dim3(Sc / 64), 512, 0, stream>>>(x2, T1p, T2p, bq1, ln1g, ln1b,
                                                 bq2, ln2g, ln2b, Wq3, bq3,
                                                 (float*)d_out + r0, NRT);
  }
}

// Round 13
// 570.044 us; speedup vs baseline: 1.5651x; 1.0805x over previous
//
#include <hip/hip_runtime.h>
#include <hip/hip_bf16.h>

typedef _Float16 f16x8 __attribute__((ext_vector_type(8)));
typedef _Float16 f16x4 __attribute__((ext_vector_type(4)));
typedef float f32x4 __attribute__((ext_vector_type(4)));

__device__ __forceinline__ float tanh_fast(float x) {
  float e = __expf(2.0f * x);
  return 1.0f - 2.0f * __builtin_amdgcn_rcpf(e + 1.0f);
}
__device__ __forceinline__ float sigmoid_fast(float x) {
  return __builtin_amdgcn_rcpf(1.0f + __expf(-x));
}

// ---------------- K0: weight prep (unchanged) ----------------
// Fragment tiles of 512 hw. PI k-order (W2, Wq1): lane l elem j holds
// B[k = kt*32 + pi(q,j)][col = nt*16 + l15], pi(q,j) = q*4 + (j&3) + 16*(j>>2).
// Plain k-order (Wq2, W1): k = q*8 + j.
// V2p tile = kt*64 + nt; T1p tile = kt*16 + nt; T2p tile = nt*8 + kt.
__global__ __launch_bounds__(256) void prep_weights(
    const float* __restrict__ W1, const float* __restrict__ W2,
    const float* __restrict__ Wq1, const float* __restrict__ Wq2,
    _Float16* __restrict__ V1p, _Float16* __restrict__ V2p,
    _Float16* __restrict__ T1p, _Float16* __restrict__ T2p) {
  __shared__ float S[32 * 33];
  int b = blockIdx.x, t = threadIdx.x;
  if (b < 2624) {
    const float* in; _Float16* out; int N, nc0, tile, use_pi;
    if (b < 2048) {        // W2 [32][1024][32]: h, ntl, kt  (PI)
      int h = b >> 6, rem = b & 63, ntl = rem >> 5, kt = rem & 31;
      in = W2 + (size_t)h * 32768 + (size_t)kt * 32 * 32;
      N = 32; nc0 = ntl * 16;
      out = V2p; tile = kt * 64 + (h * 2 + ntl); use_pi = 1;
    } else if (b < 2560) { // Wq1 [1024][256]  (PI)
      int i = b - 2048, nt = i >> 5, kt = i & 31;
      in = Wq1 + (size_t)kt * 32 * 256; N = 256; nc0 = nt * 16;
      out = T1p; tile = kt * 16 + nt; use_pi = 1;
    } else {               // Wq2 [256][128]  (plain)
      int i = b - 2560, nt = i >> 3, kt = i & 7;
      in = Wq2 + (size_t)kt * 32 * 128; N = 128; nc0 = nt * 16;
      out = T2p; tile = nt * 8 + kt; use_pi = 0;
    }
    if (t < 128) {
      int r = t >> 2, c4 = (t & 3) * 4;
      const float4 v = *(const float4*)(in + (size_t)r * N + nc0 + c4);
      S[r * 17 + c4 + 0] = v.x; S[r * 17 + c4 + 1] = v.y;
      S[r * 17 + c4 + 2] = v.z; S[r * 17 + c4 + 3] = v.w;
    }
    __syncthreads();
    if (t < 128) {
      int w2 = t >> 6, l = t & 63, q = l >> 4, l15 = l & 15;
      f16x4 o;
#pragma unroll
      for (int jj = 0; jj < 4; ++jj) {
        int kl = use_pi ? (q * 4 + jj + w2 * 16) : (q * 8 + w2 * 4 + jj);
        o[jj] = (_Float16)S[kl * 17 + l15];
      }
      *(f16x4*)(out + (size_t)tile * 512 + l * 8 + w2 * 4) = o;
    }
  } else {                 // W1 [32][32][32]: one block per head h (plain)
    int h = b - 2624;
    const float* in = W1 + h * 1024;
    int cc = t & 31, rr8 = t >> 5;
#pragma unroll
    for (int p = 0; p < 4; ++p) {
      int r = rr8 + p * 8;
      S[cc * 33 + r] = in[r * 32 + cc];
    }
    __syncthreads();
    if (t < 128) {
      int ntl = t >> 6, l = t & 63, q = l >> 4, l15 = l & 15;
      f16x8 o;
#pragma unroll
      for (int j = 0; j < 8; ++j)
        o[j] = (_Float16)S[(ntl * 16 + l15) * 33 + q * 8 + j];
      *(f16x8*)(V1p + (size_t)(h * 2 + ntl) * 512 + l * 8) = o;
    }
  }
}

// ---------------- K12: fused ripple1+ripple2, 64x1024 blocks (r4 verified) --
// Block = 64 rows x FULL 1024 cols, 512 threads = 8 waves; wave = 64 rows x
// 128 cols (nt0 = w*8), acc[4][8]. Ripple1 redundancy = 1x. 3 barriers/block;
// ph1 production interleaved at ktl==6/10 into the other buffer. xab[2][4]
// register ping-pong. LDS 136 KB -> 1 block/CU, 2 waves/SIMD (unified
// VGPR/AGPR file: acc 128 AGPR + ~128 VGPR = 256 cap). launch_bounds MUST
// stay (512,2) — (512,4) forces VGPR=64 and catastrophic spill (r5).
// Measured 90.4 (r4 env) / 120.5 (r12 env) — env-variance, not code.
__global__ __launch_bounds__(512, 2) void k12_fused(
    const float* __restrict__ state, const float* __restrict__ action,
    const _Float16* __restrict__ v1p, const float* __restrict__ b1,
    const float* __restrict__ g1,
    const _Float16* __restrict__ v2p, const float* __restrict__ b2,
    const float* __restrict__ g2,
    _Float16* __restrict__ x2p, int gro, int NRT) {
  __shared__ __align__(16) _Float16 SA[64 * 40];          // 5 KB
  __shared__ __align__(16) _Float16 XB[2][16 * 4 * 512];  // 2 x 64 KB
  int bm = blockIdx.x;
  int t = threadIdx.x, w = t >> 6, l = t & 63, q = l >> 4, l15 = l & 15;
  int m0 = bm * 64;

  {  // stage sa tile [64][32] fp16, stride 40; 8 threads/row (4 floats each)
    int r = t >> 3, qq = t & 7;
    size_t grow = (size_t)(gro + m0 + r);
    const float* src = (qq < 6) ? (state + grow * 24 + qq * 4)
                                : (action + grow * 8 + (qq - 6) * 4);
    float4 v = *(const float4*)src;
    f16x4 h;
    h[0] = (_Float16)v.x; h[1] = (_Float16)v.y;
    h[2] = (_Float16)v.z; h[3] = (_Float16)v.w;
    *(f16x4*)&SA[r * 40 + qq * 4] = h;
  }
  __syncthreads();

  // loop-invariant sa fragments (B operand of producer MFMAs), 64 rows
  f16x8 asa[4];
#pragma unroll
  for (int p = 0; p < 4; ++p)
    asa[p] = *(const f16x8*)&SA[(p * 16 + l15) * 40 + q * 8];

  const int nt0 = w * 8;
  const _Float16* bBase = v2p + (size_t)nt0 * 512 + (size_t)l * 8;
  f32x4 acc[4][8] = {};

  // produce head h (x1 cols h*32..h*32+31) for the block's 64 rows into
  // XB[buf] tiles (h&15)*4 + p. Content layout identical to verified kernel.
  auto produce = [&](int h, int buf) {
    f16x8 rb0 = *(const f16x8*)(v1p + (size_t)(2 * h) * 512 + l * 8);
    f16x8 rb1 = *(const f16x8*)(v1p + (size_t)(2 * h + 1) * 512 + l * 8);
    float sg = sigmoid_fast(g1[h]);
    f32x4 bs0 = *(const f32x4*)(b1 + h * 32 + q * 4);
    f32x4 bs1 = *(const f32x4*)(b1 + h * 32 + 16 + q * 4);
    _Float16* bw = &XB[buf][(size_t)((h & 15) * 4) * 512 + l * 8];
#pragma unroll
    for (int p = 0; p < 4; ++p) {
      f32x4 d0 = {}, d1 = {};
      d0 = __builtin_amdgcn_mfma_f32_16x16x32_f16(rb0, asa[p], d0, 0, 0, 0);
      d1 = __builtin_amdgcn_mfma_f32_16x16x32_f16(rb1, asa[p], d1, 0, 0, 0);
      f16x8 o;
#pragma unroll
      for (int r = 0; r < 4; ++r) {
        o[r]     = (_Float16)(tanh_fast(d0[r] + bs0[r]) * sg);
        o[4 + r] = (_Float16)(tanh_fast(d1[r] + bs1[r]) * sg);
      }
      *(f16x8*)(bw + (size_t)p * 512) = o;
    }
  };

  // prologue: B stream kt=0 (latency hidden under produce) + produce ph0
  f16x8 bb0[4], bb1v[4];
#pragma unroll
  for (int n2 = 0; n2 < 4; ++n2)
    bb0[n2] = *(const f16x8*)(bBase + (size_t)n2 * 512);
#pragma unroll
  for (int n2 = 0; n2 < 4; ++n2)
    bb1v[n2] = *(const f16x8*)(bBase + (size_t)(4 + n2) * 512);
  produce(w * 2, 0);
  produce(w * 2 + 1, 0);
  __syncthreads();

  f16x8 xab[2][4];
#pragma unroll
  for (int mi = 0; mi < 4; ++mi)
    xab[0][mi] = *(const f16x8*)&XB[0][(size_t)mi * 512 + l * 8];

  // phase 0: kt 0..15 from XB[0]; interleave production of heads 16..31
#pragma unroll
  for (int ktl = 0; ktl < 16; ++ktl) {
    int kt = ktl;
    if (ktl == 6)  produce(16 + w * 2, 1);
    if (ktl == 10) produce(16 + w * 2 + 1, 1);
    if (ktl < 15) {
#pragma unroll
      for (int mi = 0; mi < 4; ++mi)
        xab[(ktl + 1) & 1][mi] =
            *(const f16x8*)&XB[0][(size_t)((ktl + 1) * 4 + mi) * 512 + l * 8];
    }
    // half 0 (ni 0..3)
#pragma unroll
    for (int mi = 0; mi < 4; ++mi)
#pragma unroll
      for (int n2 = 0; n2 < 4; ++n2)
        acc[mi][n2] = __builtin_amdgcn_mfma_f32_16x16x32_f16(
            bb0[n2], xab[ktl & 1][mi], acc[mi][n2], 0, 0, 0);
#pragma unroll
    for (int n2 = 0; n2 < 4; ++n2)
      bb0[n2] = *(const f16x8*)(bBase + (size_t)((kt + 1) * 64 + n2) * 512);
    // half 1 (ni 4..7)
#pragma unroll
    for (int mi = 0; mi < 4; ++mi)
#pragma unroll
      for (int n2 = 0; n2 < 4; ++n2)
        acc[mi][4 + n2] = __builtin_amdgcn_mfma_f32_16x16x32_f16(
            bb1v[n2], xab[ktl & 1][mi], acc[mi][4 + n2], 0, 0, 0);
#pragma unroll
    for (int n2 = 0; n2 < 4; ++n2)
      bb1v[n2] = *(const f16x8*)(bBase + (size_t)((kt + 1) * 64 + 4 + n2) * 512);
  }
  __syncthreads();

#pragma unroll
  for (int mi = 0; mi < 4; ++mi)
    xab[0][mi] = *(const f16x8*)&XB[1][(size_t)mi * 512 + l * 8];

  // phase 1: kt 16..31 from XB[1]
#pragma unroll
  for (int ktl = 0; ktl < 16; ++ktl) {
    int kt = 16 + ktl;
    if (ktl < 15) {
#pragma unroll
      for (int mi = 0; mi < 4; ++mi)
        xab[(ktl + 1) & 1][mi] =
            *(const f16x8*)&XB[1][(size_t)((ktl + 1) * 4 + mi) * 512 + l * 8];
    }
    // half 0 (ni 0..3)
#pragma unroll
    for (int mi = 0; mi < 4; ++mi)
#pragma unroll
      for (int n2 = 0; n2 < 4; ++n2)
        acc[mi][n2] = __builtin_amdgcn_mfma_f32_16x16x32_f16(
            bb0[n2], xab[ktl & 1][mi], acc[mi][n2], 0, 0, 0);
    if (kt < 31) {
#pragma unroll
      for (int n2 = 0; n2 < 4; ++n2)
        bb0[n2] = *(const f16x8*)(bBase + (size_t)((kt + 1) * 64 + n2) * 512);
    }
    // half 1 (ni 4..7)
#pragma unroll
    for (int mi = 0; mi < 4; ++mi)
#pragma unroll
      for (int n2 = 0; n2 < 4; ++n2)
        acc[mi][4 + n2] = __builtin_amdgcn_mfma_f32_16x16x32_f16(
            bb1v[n2], xab[ktl & 1][mi], acc[mi][4 + n2], 0, 0, 0);
    if (kt < 31) {
#pragma unroll
      for (int n2 = 0; n2 < 4; ++n2)
        bb1v[n2] = *(const f16x8*)(bBase + (size_t)((kt + 1) * 64 + 4 + n2) * 512);
    }
  }

  // epilogue: tanh+gate in registers -> direct fragment-major x2p stores
#pragma unroll
  for (int mi = 0; mi < 4; ++mi) {
    int rt = bm * 4 + mi;
#pragma unroll
    for (int p2 = 0; p2 < 4; ++p2) {
      int kc2 = (nt0 >> 1) + p2;
      float sg2 = sigmoid_fast(g2[kc2]);
      f32x4 c0 = *(const f32x4*)(b2 + kc2 * 32 + q * 4);
      f32x4 c1 = *(const f32x4*)(b2 + kc2 * 32 + 16 + q * 4);
      f16x8 o;
#pragma unroll
      for (int r = 0; r < 4; ++r) {
        o[r]     = (_Float16)(tanh_fast(acc[mi][2 * p2][r] + c0[r]) * sg2);
        o[4 + r] = (_Float16)(tanh_fast(acc[mi][2 * p2 + 1][r] + c1[r]) * sg2);
      }
      *(f16x8*)(x2p + ((size_t)kc2 * NRT + rt) * 512 + l * 8) = o;
    }
  }
}

// ---------------- K3: q-network head, 32-row blocks ----------------
// Same verified tail math as r8-r12, with 32-row blocks: grid = Sc/32 (2x),
// per-block work halved (acc2[2][2], aC/aN[2]), peak regs ~90 << 128 ->
// __launch_bounds__(512,4) guarantees 4 waves/SIMD (the 64-row version at
// (512,3)/cap-170 may have sat at 2). Doubles latency-hiding for the
// L3-resident x2 reads; queued blocks smooth the tail. LDS ~22 KB.
// Wave w owns q1 cols w*32..w*32+31 (T1p tiles kt*16 + w*2{,+1}) and y2
// col-tile nt=w. rt0 = bm*2 (2 row-tiles of 16).
__global__ __launch_bounds__(512, 4) void k3_head32(
    const _Float16* __restrict__ x2p, const _Float16* __restrict__ t1p,
    const _Float16* __restrict__ t2p,
    const float* __restrict__ bq1, const float* __restrict__ ln1g,
    const float* __restrict__ ln1b,
    const float* __restrict__ bq2, const float* __restrict__ ln2g,
    const float* __restrict__ ln2b,
    const float* __restrict__ wq3, const float* __restrict__ bq3,
    float* __restrict__ out, int NRT) {
  __shared__ __align__(16) _Float16 y1h[32 * 268];       // 16.8 KB
  __shared__ float redA[32 * 8], redB[32 * 8];           // 2 KB
  __shared__ float meanv[32], rstdv[32];                 // 0.25 KB
  int bm = blockIdx.x;
  int t = threadIdx.x, w = t >> 6, l = t & 63, q = l >> 4, l15 = l & 15;
  int rt0 = bm * 2;

  // q1 GEMM: kt 0..31, A from gmem x2p (tile kt*NRT + rt0+mi), B from t1p
  // (tile kt*16 + w*2+ni); 1-deep prefetch on both.
  f32x4 acc2[2][2] = {};
  {
    const _Float16* aBase = x2p + (size_t)rt0 * 512 + (size_t)l * 8;
    const size_t aK = (size_t)NRT * 512;
    f16x8 aC[2], aN[2], bf0C, bf1C, bf0N, bf1N;
#pragma unroll
    for (int mi = 0; mi < 2; ++mi)
      aC[mi] = *(const f16x8*)(aBase + (size_t)mi * 512);
    bf0C = *(const f16x8*)(t1p + (size_t)(w * 2) * 512 + l * 8);
    bf1C = *(const f16x8*)(t1p + (size_t)(w * 2 + 1) * 512 + l * 8);
#pragma unroll
    for (int kt = 0; kt < 32; ++kt) {
      if (kt < 31) {
#pragma unroll
        for (int mi = 0; mi < 2; ++mi)
          aN[mi] = *(const f16x8*)(aBase + (size_t)(kt + 1) * aK + (size_t)mi * 512);
        bf0N = *(const f16x8*)(t1p + (size_t)((kt + 1) * 16 + w * 2) * 512 + l * 8);
        bf1N = *(const f16x8*)(t1p + (size_t)((kt + 1) * 16 + w * 2 + 1) * 512 + l * 8);
      }
#pragma unroll
      for (int mi = 0; mi < 2; ++mi) {
        acc2[mi][0] = __builtin_amdgcn_mfma_f32_16x16x32_f16(aC[mi], bf0C, acc2[mi][0], 0, 0, 0);
        acc2[mi][1] = __builtin_amdgcn_mfma_f32_16x16x32_f16(aC[mi], bf1C, acc2[mi][1], 0, 0, 0);
      }
#pragma unroll
      for (int mi = 0; mi < 2; ++mi) aC[mi] = aN[mi];
      bf0C = bf0N; bf1C = bf1N;
    }
  }

  // bias + LN over 256 cols
#pragma unroll
  for (int ni = 0; ni < 2; ++ni) {
    int col = w * 32 + ni * 16 + l15;
    float b = bq1[col];
#pragma unroll
    for (int mi = 0; mi < 2; ++mi)
#pragma unroll
      for (int r = 0; r < 4; ++r) acc2[mi][ni][r] += b;
  }
#pragma unroll
  for (int mi = 0; mi < 2; ++mi)
#pragma unroll
    for (int r = 0; r < 4; ++r) {
      int row = mi * 16 + q * 4 + r;
      float s = 0.f, sq = 0.f;
#pragma unroll
      for (int ni = 0; ni < 2; ++ni) { float v = acc2[mi][ni][r]; s += v; sq += v * v; }
#pragma unroll
      for (int off = 1; off < 16; off <<= 1) { s += __shfl_xor(s, off); sq += __shfl_xor(sq, off); }
      if (l15 == 0) { redA[row * 8 + w] = s; redB[row * 8 + w] = sq; }
    }
  __syncthreads();
  if (t < 32) {
    float s = 0.f, sq = 0.f;
#pragma unroll
    for (int i = 0; i < 8; ++i) { s += redA[t * 8 + i]; sq += redB[t * 8 + i]; }
    float mean = s * (1.0f / 256.0f);
    float var = sq * (1.0f / 256.0f) - mean * mean;
    meanv[t] = mean; rstdv[t] = rsqrtf(var + 1e-5f);
  }
  __syncthreads();
#pragma unroll
  for (int mi = 0; mi < 2; ++mi)
#pragma unroll
    for (int ni = 0; ni < 2; ++ni)
#pragma unroll
      for (int r = 0; r < 4; ++r) {
        int row = mi * 16 + q * 4 + r;
        int col = w * 32 + ni * 16 + l15;
        float y = (acc2[mi][ni][r] - meanv[row]) * rstdv[row] * ln1g[col] + ln1b[col];
        y = fmaxf(y, 0.f);
        y1h[row * 268 + col] = (_Float16)y;
      }
  __syncthreads();

  // y2 GEMM: wave w owns cols w*16..w*16+15 (T2p tile nt=w, plain k-order)
  f32x4 a3[2] = {};
  for (int kt = 0; kt < 8; ++kt) {
    f16x8 af[2];
#pragma unroll
    for (int mi = 0; mi < 2; ++mi)
      af[mi] = *(const f16x8*)&y1h[(mi * 16 + l15) * 268 + kt * 32 + q * 8];
    f16x8 bf = *(const f16x8*)(t2p + (size_t)(w * 8 + kt) * 512 + l * 8);
#pragma unroll
    for (int mi = 0; mi < 2; ++mi)
      a3[mi] = __builtin_amdgcn_mfma_f32_16x16x32_f16(af[mi], bf, a3[mi], 0, 0, 0);
  }
  {
    int col = w * 16 + l15;
    float b = bq2[col];
#pragma unroll
    for (int mi = 0; mi < 2; ++mi)
#pragma unroll
      for (int r = 0; r < 4; ++r) a3[mi][r] += b;
  }
  __syncthreads();  // y1h reads done; redA/redB reuse safe
#pragma unroll
  for (int mi = 0; mi < 2; ++mi)
#pragma unroll
    for (int r = 0; r < 4; ++r) {
      int row = mi * 16 + q * 4 + r;
      float s = a3[mi][r], sq = s * s;
#pragma unroll
      for (int off = 1; off < 16; off <<= 1) { s += __shfl_xor(s, off); sq += __shfl_xor(sq, off); }
      if (l15 == 0) { redA[row * 8 + w] = s; redB[row * 8 + w] = sq; }
    }
  __syncthreads();
  if (t < 32) {
    float s = 0.f, sq = 0.f;
#pragma unroll
    for (int i = 0; i < 8; ++i) { s += redA[t * 8 + i]; sq += redB[t * 8 + i]; }
    float mean = s * (1.0f / 128.0f);
    float var = sq * (1.0f / 128.0f) - mean * mean;
    meanv[t] = mean; rstdv[t] = rsqrtf(var + 1e-5f);
  }
  __syncthreads();
#pragma unroll
  for (int mi = 0; mi < 2; ++mi)
#pragma unroll
    for (int r = 0; r < 4; ++r) {
      int row = mi * 16 + q * 4 + r;
      int col = w * 16 + l15;
      float y = (a3[mi][r] - meanv[row]) * rstdv[row] * ln2g[col] + ln2b[col];
      y = fmaxf(y, 0.f);
      float pr = y * wq3[col];
#pragma unroll
      for (int off = 1; off < 16; off <<= 1) pr += __shfl_xor(pr, off);
      if (l15 == 0) redA[row * 8 + w] = pr;
    }
  __syncthreads();
  if (t < 32) {
    float s = 0.f;
#pragma unroll
    for (int i = 0; i < 8; ++i) s += redA[t * 8 + i];
    out[bm * 32 + t] = s + bq3[0];
  }
}

// ---------------- launcher ----------------
extern "C" void kernel_launch(void* const* d_in, const int* in_sizes, int n_in,
                              void* d_out, int out_size, void* d_ws, size_t ws_size,
                              hipStream_t stream) {
  const float* state  = (const float*)d_in[0];
  const float* action = (const float*)d_in[1];
  const float* W1  = (const float*)d_in[2];
  const float* b1  = (const float*)d_in[3];
  const float* g1  = (const float*)d_in[4];
  const float* W2  = (const float*)d_in[5];
  const float* b2  = (const float*)d_in[6];
  const float* g2  = (const float*)d_in[7];
  const float* Wq1 = (const float*)d_in[8];
  const float* bq1 = (const float*)d_in[9];
  const float* ln1g = (const float*)d_in[10];
  const float* ln1b = (const float*)d_in[11];
  const float* Wq2 = (const float*)d_in[12];
  const float* bq2 = (const float*)d_in[13];
  const float* ln2g = (const float*)d_in[14];
  const float* ln2b = (const float*)d_in[15];
  const float* Wq3 = (const float*)d_in[16];
  const float* bq3 = (const float*)d_in[17];
  int B = in_sizes[0] / 24;

  char* ws = (char*)d_ws;
  _Float16* V1p = (_Float16*)(ws);
  _Float16* V2p = (_Float16*)(ws + 65536);
  _Float16* T1p = (_Float16*)(ws + 65536 + 2097152);
  _Float16* T2p = (_Float16*)(ws + 65536 + 2097152 + 524288);
  size_t woff = (65536 + 2097152 + 524288 + 65536 + 4095) & ~(size_t)4095;

  size_t avail = ws_size > woff ? ws_size - woff : 0;
  long rows = (long)(avail / 2048);     // x2 fp16 1024-wide
  if (rows > 65536) rows = 65536;       // 128 MB x2, still L3-resident;
  rows &= ~127L;                        // halves slice-boundary drains
  if (rows < 128) rows = 128;
  int S = (int)rows;
  _Float16* x2 = (_Float16*)(ws + woff);
  int NRT = S / 16;

  prep_weights<<<2656, 256, 0, stream>>>(W1, W2, Wq1, Wq2, V1p, V2p, T1p, T2p);

  for (int r0 = 0; r0 < B; r0 += S) {
    int Sc = S < (B - r0) ? S : (B - r0);
    k12_fused<<<dim3(Sc / 64), 512, 0, stream>>>(state, action, V1p, b1, g1,
                                                 V2p, b2, g2, x2, r0, NRT);
    k3_head32<<<dim3(Sc / 32), 512, 0, stream>>>(x2, T1p, T2p, bq1, ln1g, ln1b,
                                                 bq2, ln2g, ln2b, Wq3, bq3,
                                                 (float*)d_out + r0, NRT);
  }
}